// Round 12
// baseline (92.980 us; speedup 1.0000x reference)
//
#include <hip/hip_runtime.h>
#include <hip/hip_bf16.h>

// LiftedStructureLoss on MI355X (gfx950)
// N=8192, D=128 fp32 embeddings; int labels (0..99); scalar fp32 out.
//
// 3 launches:
//   setup:  blocks 0..255 = prep (sq, bf16 convert, both log2e-prescaled);
//           block 256 = bucket (zero+hist+scan+scatter, zero ticket)
//   pass1:  upper-triangle 128x128 tiles, 512 thr, 2-chunk global_load_lds
//           staging; row+col sums of 2^(-sqrt(d2s)) = exp(-d) over negatives
//           -> partial1[cb][row]  (no global atomics; R6 structure, 39.6us)
//   pass2:  per-label blocks; prologue gathers this label's sum_exp rows from
//           partial1 into LDS (x e, folding MARGIN exp); within-label Gram
//           (~1% of pairs) -> loss + n_pos; ticket: last block -> out
//
// Scaling: ebf and sq carry a log2e factor, so d2s = (log2e*d)^2 and
// v_exp_f32(-sqrt(d2s)) = 2^(-log2e*d) = exp(-d); pass2's dist = sqrt(d2s)*ln2.

typedef __attribute__((ext_vector_type(8))) short bf16x8;
typedef __attribute__((ext_vector_type(4))) float f32x4;

#if __has_builtin(__builtin_amdgcn_exp2f)
#define EXP2F __builtin_amdgcn_exp2f
#else
#define EXP2F exp2f
#endif

__device__ __forceinline__ unsigned short f2bf(float f) {
    unsigned u = __float_as_uint(f);
    u += 0x7fffu + ((u >> 16) & 1u);   // round-to-nearest-even
    return (unsigned short)(u >> 16);
}

// Blocks 0..nPrep-1: prep 32 rows each (4 waves x 8 rows), log2e-prescaled.
// Block nPrep: bucket labels (256 threads).
__global__ __launch_bounds__(256) void setup_kernel(
    const float* __restrict__ e, const int* __restrict__ labels,
    float* __restrict__ sq, unsigned* __restrict__ ebf,
    int* __restrict__ counts_out, int* __restrict__ offsets_out,
    int* __restrict__ idxbuf, unsigned* __restrict__ ticket, int N)
{
    const int tid = threadIdx.x;
    const float LOG2E = 1.44269504088896341f;
    if ((int)blockIdx.x < (int)gridDim.x - 1) {
        const int lane = tid & 63, wid = tid >> 6;
        const int rowbase = (blockIdx.x * 4 + wid) * 8;
        #pragma unroll
        for (int it = 0; it < 8; ++it) {
            int row = rowbase + it;
            if (row >= N) break;
            float2 v = ((const float2*)(e + (size_t)row * 128))[lane];
            v.x *= LOG2E; v.y *= LOG2E;
            float s = v.x * v.x + v.y * v.y;
            #pragma unroll
            for (int off = 1; off < 64; off <<= 1) s += __shfl_xor(s, off, 64);
            if (lane == 0) sq[row] = s;
            unsigned bits = (unsigned)f2bf(v.x) | ((unsigned)f2bf(v.y) << 16);
            ebf[(size_t)row * 64 + lane] = bits;
        }
    } else {
        __shared__ int cnt[256];
        __shared__ int off[256];
        if (tid == 0) *ticket = 0u;
        cnt[tid] = 0;
        __syncthreads();
        for (int i = tid; i < N; i += 256)
            atomicAdd(&cnt[(unsigned)labels[i] & 255u], 1);
        __syncthreads();
        if (tid < 64) {
            int base = tid * 4;
            int c0 = cnt[base], c1 = cnt[base+1], c2 = cnt[base+2], c3 = cnt[base+3];
            int s = c0 + c1 + c2 + c3;
            int v = s;
            #pragma unroll
            for (int d = 1; d < 64; d <<= 1) {
                int u = __shfl_up(v, d, 64);
                if (tid >= d) v += u;
            }
            int excl = v - s;
            off[base]     = excl;
            off[base + 1] = excl + c0;
            off[base + 2] = excl + c0 + c1;
            off[base + 3] = excl + c0 + c1 + c2;
        }
        __syncthreads();
        counts_out[tid]  = cnt[tid];
        offsets_out[tid] = off[tid];
        cnt[tid] = off[tid];               // reuse as cursor
        __syncthreads();
        for (int i = tid; i < N; i += 256) {
            int l = (unsigned)labels[i] & 255u;
            int p = atomicAdd(&cnt[l], 1);
            idxbuf[p] = i;
        }
    }
}

// PASS 1 (R6 structure): one 128x128 upper-triangle tile per block, 512 thr =
// 8 waves of 64x32. K=128 in 2 chunks of 64, async global_load_lds staging
// (linear LDS dest + inverse-swizzled global src), swizzled ds_read.
__global__ __launch_bounds__(512) void pass1_kernel(
    const unsigned short* __restrict__ ebf,
    const float* __restrict__ sq,
    const int* __restrict__ labels,
    float* __restrict__ partial1,      // [nCb][N]
    int N, int nCb)
{
    __shared__ __align__(16) char a_tile[128 * 128];  // one K-chunk (64 cols)
    __shared__ __align__(16) char b_tile[128 * 128];
    __shared__ float rowsum[128];
    __shared__ float colsum[128];

    const int tid = threadIdx.x;
    const int lane = tid & 63, wid = tid >> 6;

    // decode linear tile id -> (bi, bj), bi <= bj
    const int t = blockIdx.x;
    int bi = (int)((2.f * nCb + 1.f - __builtin_amdgcn_sqrtf(
                   (2.f * nCb + 1.f) * (2.f * nCb + 1.f) - 8.f * t)) * 0.5f);
    if (bi < 0) bi = 0;
    if (bi > nCb - 1) bi = nCb - 1;
    while (bi + 1 <= nCb - 1 && (bi + 1) * (2 * nCb - bi) / 2 <= t) ++bi;
    while (bi > 0 && bi * (2 * nCb - bi + 1) / 2 > t) --bi;
    const int bj = bi + (t - bi * (2 * nCb - bi + 1) / 2);
    const bool diag = (bi == bj);
    const int brow = bi * 128, bcol = bj * 128;

    if (tid < 128) { rowsum[tid] = 0.f; colsum[tid] = 0.f; }

    const int wm = (wid >> 2) * 64, wn = (wid & 3) * 32;
    const int lhi = lane >> 4, llo = lane & 15;
    const char* ebfB = (const char*)ebf;

    f32x4 acc[4][2];
    #pragma unroll
    for (int m = 0; m < 4; ++m)
        #pragma unroll
        for (int n = 0; n < 2; ++n)
            acc[m][n] = (f32x4){0.f, 0.f, 0.f, 0.f};

    #pragma unroll
    for (int c = 0; c < 2; ++c) {
        // async stage: 2048 16B slots, wave wid covers [wid*256, +256)
        #pragma unroll
        for (int k = 0; k < 4; ++k) {
            int s = wid * 256 + k * 64;          // wave-uniform slot base
            int tsel = s >> 10;                  // 0: a_tile, 1: b_tile
            int ls = s & 1023;
            int sl = ls + lane;                  // per-lane slot within tile
            int r = sl >> 3, j = sl & 7;
            int grow = (tsel ? bcol : brow) + r;
            const void* g = ebfB + ((size_t)grow << 8) + c * 128 + ((j ^ (r & 7)) << 4);
            char* l = (tsel ? b_tile : a_tile) + ls * 16;   // wave-uniform
            __builtin_amdgcn_global_load_lds(
                (const __attribute__((address_space(1))) unsigned*)g,
                (__attribute__((address_space(3))) unsigned*)l, 16, 0, 0);
        }
        __syncthreads();   // drains vmcnt before ds_read

        #pragma unroll
        for (int h = 0; h < 2; ++h) {
            const int cb = h * 64 + lhi * 16;
            bf16x8 af[4], bfr[2];
            #pragma unroll
            for (int m = 0; m < 4; ++m) {
                int r = wm + m * 16 + llo;
                af[m] = *(const bf16x8*)(a_tile + r * 128 + (cb ^ ((r & 7) << 4)));
            }
            #pragma unroll
            for (int n = 0; n < 2; ++n) {
                int r = wn + n * 16 + llo;
                bfr[n] = *(const bf16x8*)(b_tile + r * 128 + (cb ^ ((r & 7) << 4)));
            }
            #pragma unroll
            for (int m = 0; m < 4; ++m)
                #pragma unroll
                for (int n = 0; n < 2; ++n)
                    acc[m][n] = __builtin_amdgcn_mfma_f32_16x16x32_bf16(af[m], bfr[n], acc[m][n], 0, 0, 0);
        }
        __syncthreads();
    }

    // ---- epilogue: masked exp sums ----
    // C/D layout: col = lane&15, row = (lane>>4)*4 + reg
    const int rowbase = brow + wm;
    float sqr[4][4]; int labr[4][4];
    #pragma unroll
    for (int m = 0; m < 4; ++m)
        #pragma unroll
        for (int r = 0; r < 4; ++r) {
            int row = rowbase + m * 16 + lhi * 4 + r;
            sqr[m][r] = sq[row];
            labr[m][r] = labels[row];
        }
    float sqc[2]; int labc[2];
    #pragma unroll
    for (int n = 0; n < 2; ++n) {
        int col = bcol + wn + n * 16 + llo;
        sqc[n] = sq[col];
        labc[n] = labels[col];
    }

    float wsum[4][4] = {};
    float csum[2] = {};
    #pragma unroll
    for (int m = 0; m < 4; ++m)
        #pragma unroll
        for (int n = 0; n < 2; ++n)
            #pragma unroll
            for (int r = 0; r < 4; ++r) {
                float g = acc[m][n][r];
                float d2 = fmaxf(fmaf(-2.f, g, sqr[m][r] + sqc[n]), 0.f);
                float dist = __builtin_amdgcn_sqrtf(d2);   // log2e * d
                float w = (labr[m][r] != labc[n]) ? EXP2F(0.f - dist) : 0.f;
                wsum[m][r] += w;
                csum[n] += w;
            }
    // row sums: reduce across 16 llo lanes
    #pragma unroll
    for (int m = 0; m < 4; ++m)
        #pragma unroll
        for (int r = 0; r < 4; ++r) {
            float s = wsum[m][r];
            #pragma unroll
            for (int off = 1; off < 16; off <<= 1) s += __shfl_xor(s, off, 64);
            if (llo == 0)
                atomicAdd(&rowsum[wm + m * 16 + lhi * 4 + r], s);
        }
    // col sums: reduce across the 4 lhi groups
    if (!diag) {
        #pragma unroll
        for (int n = 0; n < 2; ++n) {
            float s = csum[n];
            s += __shfl_xor(s, 16, 64);
            s += __shfl_xor(s, 32, 64);
            if (lhi == 0)
                atomicAdd(&colsum[wn + n * 16 + llo], s);
        }
    }
    __syncthreads();
    if (tid < 128) {
        partial1[(size_t)bj * N + brow + tid] = rowsum[tid];
        if (!diag)
            partial1[(size_t)bi * N + bcol + tid] = colsum[tid];
    }
}

// PASS 2: one block per label. Prologue: gather this label's sum_exp rows
// from partial1 into LDS (x e). Then within-label Gram + loss (ordered).
// Last block (ticket) reduces partial2/cnt2 -> out.
__global__ __launch_bounds__(256) void pass2_kernel(
    const unsigned short* __restrict__ ebf,
    const float* __restrict__ sq,
    const float* __restrict__ partial1,   // [nCb][N]
    const int* __restrict__ idxbuf,
    const int* __restrict__ offsets,
    const int* __restrict__ counts,
    double* __restrict__ partial2,
    unsigned* __restrict__ cnt2,
    unsigned* __restrict__ ticket,
    float* __restrict__ out,
    int N, int nCb)
{
    __shared__ __align__(16) char a_tile[128 * 128];
    __shared__ __align__(16) char b_tile[128 * 128];
    __shared__ float se_lds[1024];
    __shared__ double bsum[4];
    __shared__ unsigned bcnt[4];
    __shared__ bool isLast;

    const int L = blockIdx.x;
    const int NL = gridDim.x;
    const int tid = threadIdx.x;
    const int lane = tid & 63, wid = tid >> 6;
    const int cnt = counts[L], offs = offsets[L];
    const int wm = (wid >> 1) * 64, wn = (wid & 1) * 64;
    const int lhi = lane >> 4, llo = lane & 15;
    const char* ebfB = (const char*)ebf;
    const float E1 = 2.71828182845904523f;
    const float LN2 = 0.69314718055994531f;

    // ---- prologue: sum_exp for this label's rows (fold e) ----
    const int cnt_c = min(cnt, 1024);
    for (int i = tid; i < cnt_c; i += 256) {
        int gi = idxbuf[offs + i];
        float s = 0.f;
        for (int cb = 0; cb < nCb; ++cb) s += partial1[(size_t)cb * N + gi];
        se_lds[i] = s * E1;
    }
    __syncthreads();

    float lsum = 0.f; unsigned lcnt = 0;

    if (cnt > 1) {
        const int nSub = (cnt + 127) >> 7;
        for (int si = 0; si < nSub; ++si)
        for (int sj = si; sj < nSub; ++sj) {
            const int baseA = offs + si * 128, baseB = offs + sj * 128;
            const int cntA = min(128, cnt - si * 128);
            const int cntB = min(128, cnt - sj * 128);
            const float wgt = (si == sj) ? 1.f : 2.f;
            const unsigned wgtu = (si == sj) ? 1u : 2u;

            f32x4 acc[4][4];
            #pragma unroll
            for (int m = 0; m < 4; ++m)
                #pragma unroll
                for (int n = 0; n < 4; ++n)
                    acc[m][n] = (f32x4){0.f, 0.f, 0.f, 0.f};

            for (int c = 0; c < 2; ++c) {
                #pragma unroll
                for (int i2 = 0; i2 < 8; ++i2) {
                    int sl = tid + i2 * 256;
                    int tsel = sl >> 10;
                    int s = sl & 1023;
                    int r = s >> 3, j = s & 7;
                    int base = tsel ? baseB : baseA;
                    int cc = tsel ? cntB : cntA;
                    int gr = idxbuf[base + min(r, cc - 1)];
                    uint4 v = *(const uint4*)(ebfB + ((size_t)gr << 8) + c * 128 + (j << 4));
                    char* tp = tsel ? b_tile : a_tile;
                    *(uint4*)(tp + r * 128 + (((j << 4)) ^ ((r & 7) << 4))) = v;
                }
                __syncthreads();
                #pragma unroll
                for (int h = 0; h < 2; ++h) {
                    const int cb = h * 64 + lhi * 16;
                    bf16x8 af[4], bfr[4];
                    #pragma unroll
                    for (int m = 0; m < 4; ++m) {
                        int r = wm + m * 16 + llo;
                        af[m] = *(const bf16x8*)(a_tile + r * 128 + (cb ^ ((r & 7) << 4)));
                    }
                    #pragma unroll
                    for (int n = 0; n < 4; ++n) {
                        int r = wn + n * 16 + llo;
                        bfr[n] = *(const bf16x8*)(b_tile + r * 128 + (cb ^ ((r & 7) << 4)));
                    }
                    #pragma unroll
                    for (int m = 0; m < 4; ++m)
                        #pragma unroll
                        for (int n = 0; n < 4; ++n)
                            acc[m][n] = __builtin_amdgcn_mfma_f32_16x16x32_bf16(af[m], bfr[n], acc[m][n], 0, 0, 0);
                }
                __syncthreads();
            }

            // epilogue: positive-pair loss
            int giA[4][4]; float sqA[4][4], seA[4][4]; bool vA[4][4];
            #pragma unroll
            for (int m = 0; m < 4; ++m)
                #pragma unroll
                for (int r = 0; r < 4; ++r) {
                    int lr = wm + m * 16 + lhi * 4 + r;
                    vA[m][r] = lr < cntA;
                    int li = min(si * 128 + min(lr, cntA - 1), 1023);
                    int gi = idxbuf[baseA + min(lr, cntA - 1)];
                    giA[m][r] = gi;
                    sqA[m][r] = sq[gi];
                    seA[m][r] = se_lds[li];
                }
            int gjB[4]; float sqB[4], seB[4]; bool vB[4];
            #pragma unroll
            for (int n = 0; n < 4; ++n) {
                int lc = wn + n * 16 + llo;
                vB[n] = lc < cntB;
                int lj = min(sj * 128 + min(lc, cntB - 1), 1023);
                int gj = idxbuf[baseB + min(lc, cntB - 1)];
                gjB[n] = gj;
                sqB[n] = sq[gj];
                seB[n] = se_lds[lj];
            }
            #pragma unroll
            for (int m = 0; m < 4; ++m)
                #pragma unroll
                for (int n = 0; n < 4; ++n)
                    #pragma unroll
                    for (int r = 0; r < 4; ++r) {
                        float g = acc[m][n][r];
                        float d2 = fmaxf(fmaf(-2.f, g, sqA[m][r] + sqB[n]), 0.f);
                        float dist = __builtin_amdgcn_sqrtf(d2) * LN2;
                        bool pos = vA[m][r] && vB[n] && (giA[m][r] != gjB[n]);
                        float Lv = __logf(seA[m][r] + seB[n]) + dist;
                        Lv = fmaxf(Lv, 0.f);
                        lsum += pos ? wgt * Lv * Lv : 0.f;
                        lcnt += pos ? wgtu : 0u;
                    }
        }
    }

    #pragma unroll
    for (int off = 1; off < 64; off <<= 1) {
        lsum += __shfl_xor(lsum, off, 64);
        lcnt += __shfl_xor(lcnt, off, 64);
    }
    if (lane == 0) { bsum[wid] = (double)lsum; bcnt[wid] = lcnt; }
    __syncthreads();
    if (tid == 0) {
        partial2[L] = bsum[0] + bsum[1] + bsum[2] + bsum[3];
        cnt2[L] = bcnt[0] + bcnt[1] + bcnt[2] + bcnt[3];
        __threadfence();
        isLast = (atomicAdd(ticket, 1u) == (unsigned)(NL - 1));
    }
    __syncthreads();

    if (isLast) {
        __threadfence();
        double tt = (tid < NL) ? partial2[tid] : 0.0;
        unsigned c = (tid < NL) ? cnt2[tid] : 0u;
        #pragma unroll
        for (int off = 1; off < 64; off <<= 1) {
            tt += __shfl_xor(tt, off, 64);
            c  += __shfl_xor(c, off, 64);
        }
        if (lane == 0) { bsum[wid] = tt; bcnt[wid] = c; }
        __syncthreads();
        if (tid == 0) {
            double s = bsum[0] + bsum[1] + bsum[2] + bsum[3];
            unsigned cc = bcnt[0] + bcnt[1] + bcnt[2] + bcnt[3];
            if (cc == 0) cc = 1;
            out[0] = (float)(s / (double)cc * 0.5);
        }
    }
}

extern "C" void kernel_launch(void* const* d_in, const int* in_sizes, int n_in,
                              void* d_out, int out_size, void* d_ws, size_t ws_size,
                              hipStream_t stream) {
    const float* e = (const float*)d_in[0];
    const int* labels = (const int*)d_in[1];
    const int N = in_sizes[1];                 // 8192
    const int nCb = N / 128;                   // 64
    const int nT = nCb * (nCb + 1) / 2;        // 2080
    const int NL = 256;
    const int nPrep = N / 32;                  // 256

    char* ws = (char*)d_ws;
    float*    sq       = (float*)ws;
    unsigned short* ebf = (unsigned short*)(ws + 4 * (size_t)N);
    char*     p        = ws + 4 * (size_t)N + 256 * (size_t)N;
    float*    partial1 = (float*)p;            // nCb*N floats (2 MB)
    p += (size_t)nCb * N * 4;
    int*      counts   = (int*)p;      p += NL * 4;
    int*      offsets  = (int*)p;      p += NL * 4;
    unsigned* ticket   = (unsigned*)p; p += 64;           // own cache line
    p = (char*)(((size_t)p + 7) & ~(size_t)7);
    double*   partial2 = (double*)p;   p += NL * 8;
    unsigned* cnt2     = (unsigned*)p; p += NL * 4;
    int*      idxbuf   = (int*)p;

    setup_kernel<<<nPrep + 1, 256, 0, stream>>>(e, labels, sq, (unsigned*)ebf,
                                                counts, offsets, idxbuf, ticket, N);
    pass1_kernel<<<nT, 512, 0, stream>>>(ebf, sq, labels, partial1, N, nCb);
    pass2_kernel<<<NL, 256, 0, stream>>>(ebf, sq, partial1, idxbuf, offsets, counts,
                                         partial2, cnt2, ticket, (float*)d_out, N, nCb);
}

// Round 13
// 73.571 us; speedup vs baseline: 1.2638x; 1.2638x over previous
//
#include <hip/hip_runtime.h>
#include <hip/hip_bf16.h>

// LiftedStructureLoss on MI355X (gfx950)
// N=8192, D=128 fp32 embeddings; int labels (0..99); scalar fp32 out.
//
// 3 launches (R9 structure + log2e prescale + XCD-swizzled pass1 tiles):
//   setup:  blocks 0..255 = prep (sq, bf16, log2e-prescaled, zero sum_exp);
//           block 256 = bucket (zero+hist+scan+scatter, zero ticket)
//   pass1:  upper-triangle 128x128 tiles (XCD-chunked tile order), 512 thr,
//           2-chunk global_load_lds staging; row+col sums of 2^(-sd) =
//           exp(-d) over negatives -> unsafeAtomicAdd(sum_exp)
//   pass2:  per-label within-label Gram (~1% of pairs) -> loss + n_pos;
//           ticket: last block reduces partials -> out
//
// Scaling: ebf/sq carry log2e, so sqrt(d2s) = log2e*d; exp2(-that) = exp(-d);
// pass2 recovers dist = sqrt(d2s)*ln2; e^1 (MARGIN) folded into pass2 reads.

typedef __attribute__((ext_vector_type(8))) short bf16x8;
typedef __attribute__((ext_vector_type(4))) float f32x4;

#if __has_builtin(__builtin_amdgcn_exp2f)
#define EXP2F __builtin_amdgcn_exp2f
#else
#define EXP2F exp2f
#endif

__device__ __forceinline__ unsigned short f2bf(float f) {
    unsigned u = __float_as_uint(f);
    u += 0x7fffu + ((u >> 16) & 1u);   // round-to-nearest-even
    return (unsigned short)(u >> 16);
}

// Blocks 0..nPrep-1: prep 32 rows each (4 waves x 8 rows) + zero sum_exp.
// Block nPrep: bucket labels (256 threads).
__global__ __launch_bounds__(256) void setup_kernel(
    const float* __restrict__ e, const int* __restrict__ labels,
    float* __restrict__ sq, unsigned* __restrict__ ebf,
    float* __restrict__ sum_exp,
    int* __restrict__ counts_out, int* __restrict__ offsets_out,
    int* __restrict__ idxbuf, unsigned* __restrict__ ticket, int N)
{
    const int tid = threadIdx.x;
    const float LOG2E = 1.44269504088896341f;
    if ((int)blockIdx.x < (int)gridDim.x - 1) {
        const int lane = tid & 63, wid = tid >> 6;
        if (tid < 32) sum_exp[blockIdx.x * 32 + tid] = 0.f;
        const int rowbase = (blockIdx.x * 4 + wid) * 8;
        #pragma unroll
        for (int it = 0; it < 8; ++it) {
            int row = rowbase + it;
            if (row >= N) break;
            float2 v = ((const float2*)(e + (size_t)row * 128))[lane];
            v.x *= LOG2E; v.y *= LOG2E;
            float s = v.x * v.x + v.y * v.y;
            #pragma unroll
            for (int off = 1; off < 64; off <<= 1) s += __shfl_xor(s, off, 64);
            if (lane == 0) sq[row] = s;
            unsigned bits = (unsigned)f2bf(v.x) | ((unsigned)f2bf(v.y) << 16);
            ebf[(size_t)row * 64 + lane] = bits;
        }
    } else {
        __shared__ int cnt[256];
        __shared__ int off[256];
        if (tid == 0) *ticket = 0u;
        cnt[tid] = 0;
        __syncthreads();
        for (int i = tid; i < N; i += 256)
            atomicAdd(&cnt[(unsigned)labels[i] & 255u], 1);
        __syncthreads();
        if (tid < 64) {
            int base = tid * 4;
            int c0 = cnt[base], c1 = cnt[base+1], c2 = cnt[base+2], c3 = cnt[base+3];
            int s = c0 + c1 + c2 + c3;
            int v = s;
            #pragma unroll
            for (int d = 1; d < 64; d <<= 1) {
                int u = __shfl_up(v, d, 64);
                if (tid >= d) v += u;
            }
            int excl = v - s;
            off[base]     = excl;
            off[base + 1] = excl + c0;
            off[base + 2] = excl + c0 + c1;
            off[base + 3] = excl + c0 + c1 + c2;
        }
        __syncthreads();
        counts_out[tid]  = cnt[tid];
        offsets_out[tid] = off[tid];
        cnt[tid] = off[tid];               // reuse as cursor
        __syncthreads();
        for (int i = tid; i < N; i += 256) {
            int l = (unsigned)labels[i] & 255u;
            int p = atomicAdd(&cnt[l], 1);
            idxbuf[p] = i;
        }
    }
}

// PASS 1: one 128x128 upper-triangle tile per block, 512 thr = 8 waves of
// 64x32. K=128 in 2 chunks of 64, async global_load_lds staging. Tile id
// XCD-swizzled: same-XCD blocks get contiguous tile ids -> row-panel L2 reuse.
__global__ __launch_bounds__(512) void pass1_kernel(
    const unsigned short* __restrict__ ebf,
    const float* __restrict__ sq,
    const int* __restrict__ labels,
    float* __restrict__ sum_exp,       // accumulated via fp32 atomics
    int N, int nCb, int nT)
{
    __shared__ __align__(16) char a_tile[128 * 128];
    __shared__ __align__(16) char b_tile[128 * 128];
    __shared__ float rowsum[128];
    __shared__ float colsum[128];

    const int tid = threadIdx.x;
    const int lane = tid & 63, wid = tid >> 6;

    // XCD-aware swizzle (bijective when nT % 8 == 0; nT=2080=8*260)
    int t;
    {
        int bid = blockIdx.x;
        if ((nT & 7) == 0) {
            int cpx = nT >> 3;
            t = (bid & 7) * cpx + (bid >> 3);
        } else {
            t = bid;
        }
    }
    // decode linear tile id -> (bi, bj), bi <= bj
    int bi = (int)((2.f * nCb + 1.f - __builtin_amdgcn_sqrtf(
                   (2.f * nCb + 1.f) * (2.f * nCb + 1.f) - 8.f * t)) * 0.5f);
    if (bi < 0) bi = 0;
    if (bi > nCb - 1) bi = nCb - 1;
    while (bi + 1 <= nCb - 1 && (bi + 1) * (2 * nCb - bi) / 2 <= t) ++bi;
    while (bi > 0 && bi * (2 * nCb - bi + 1) / 2 > t) --bi;
    const int bj = bi + (t - bi * (2 * nCb - bi + 1) / 2);
    const bool diag = (bi == bj);
    const int brow = bi * 128, bcol = bj * 128;

    if (tid < 128) { rowsum[tid] = 0.f; colsum[tid] = 0.f; }

    const int wm = (wid >> 2) * 64, wn = (wid & 3) * 32;
    const int lhi = lane >> 4, llo = lane & 15;
    const char* ebfB = (const char*)ebf;

    f32x4 acc[4][2];
    #pragma unroll
    for (int m = 0; m < 4; ++m)
        #pragma unroll
        for (int n = 0; n < 2; ++n)
            acc[m][n] = (f32x4){0.f, 0.f, 0.f, 0.f};

    #pragma unroll
    for (int c = 0; c < 2; ++c) {
        // async stage: 2048 16B slots, wave wid covers [wid*256, +256)
        #pragma unroll
        for (int k = 0; k < 4; ++k) {
            int s = wid * 256 + k * 64;          // wave-uniform slot base
            int tsel = s >> 10;                  // 0: a_tile, 1: b_tile
            int ls = s & 1023;
            int sl = ls + lane;                  // per-lane slot within tile
            int r = sl >> 3, j = sl & 7;
            int grow = (tsel ? bcol : brow) + r;
            const void* g = ebfB + ((size_t)grow << 8) + c * 128 + ((j ^ (r & 7)) << 4);
            char* l = (tsel ? b_tile : a_tile) + ls * 16;   // wave-uniform
            __builtin_amdgcn_global_load_lds(
                (const __attribute__((address_space(1))) unsigned*)g,
                (__attribute__((address_space(3))) unsigned*)l, 16, 0, 0);
        }
        __syncthreads();   // drains vmcnt before ds_read

        #pragma unroll
        for (int h = 0; h < 2; ++h) {
            const int cb = h * 64 + lhi * 16;
            bf16x8 af[4], bfr[2];
            #pragma unroll
            for (int m = 0; m < 4; ++m) {
                int r = wm + m * 16 + llo;
                af[m] = *(const bf16x8*)(a_tile + r * 128 + (cb ^ ((r & 7) << 4)));
            }
            #pragma unroll
            for (int n = 0; n < 2; ++n) {
                int r = wn + n * 16 + llo;
                bfr[n] = *(const bf16x8*)(b_tile + r * 128 + (cb ^ ((r & 7) << 4)));
            }
            #pragma unroll
            for (int m = 0; m < 4; ++m)
                #pragma unroll
                for (int n = 0; n < 2; ++n)
                    acc[m][n] = __builtin_amdgcn_mfma_f32_16x16x32_bf16(af[m], bfr[n], acc[m][n], 0, 0, 0);
        }
        __syncthreads();
    }

    // ---- epilogue: masked exp sums ----
    // C/D layout: col = lane&15, row = (lane>>4)*4 + reg
    const int rowbase = brow + wm;
    float sqr[4][4]; int labr[4][4];
    #pragma unroll
    for (int m = 0; m < 4; ++m)
        #pragma unroll
        for (int r = 0; r < 4; ++r) {
            int row = rowbase + m * 16 + lhi * 4 + r;
            sqr[m][r] = sq[row];
            labr[m][r] = labels[row];
        }
    float sqc[2]; int labc[2];
    #pragma unroll
    for (int n = 0; n < 2; ++n) {
        int col = bcol + wn + n * 16 + llo;
        sqc[n] = sq[col];
        labc[n] = labels[col];
    }

    float wsum[4][4] = {};
    float csum[2] = {};
    #pragma unroll
    for (int m = 0; m < 4; ++m)
        #pragma unroll
        for (int n = 0; n < 2; ++n)
            #pragma unroll
            for (int r = 0; r < 4; ++r) {
                float g = acc[m][n][r];
                float d2 = fmaxf(fmaf(-2.f, g, sqr[m][r] + sqc[n]), 0.f);
                float dist = __builtin_amdgcn_sqrtf(d2);   // log2e * d
                float w = (labr[m][r] != labc[n]) ? EXP2F(0.f - dist) : 0.f;
                wsum[m][r] += w;
                csum[n] += w;
            }
    // row sums: reduce across 16 llo lanes
    #pragma unroll
    for (int m = 0; m < 4; ++m)
        #pragma unroll
        for (int r = 0; r < 4; ++r) {
            float s = wsum[m][r];
            #pragma unroll
            for (int off = 1; off < 16; off <<= 1) s += __shfl_xor(s, off, 64);
            if (llo == 0)
                atomicAdd(&rowsum[wm + m * 16 + lhi * 4 + r], s);
        }
    // col sums: reduce across the 4 lhi groups
    if (!diag) {
        #pragma unroll
        for (int n = 0; n < 2; ++n) {
            float s = csum[n];
            s += __shfl_xor(s, 16, 64);
            s += __shfl_xor(s, 32, 64);
            if (lhi == 0)
                atomicAdd(&colsum[wn + n * 16 + llo], s);
        }
    }
    __syncthreads();
    if (tid < 128) {
        unsafeAtomicAdd(&sum_exp[brow + tid], rowsum[tid]);
        if (!diag)
            unsafeAtomicAdd(&sum_exp[bcol + tid], colsum[tid]);
    }
}

// PASS 2: one block per label; within-label Gram + loss (ordered counting).
// Last block (ticket) reduces partial2/cnt2 -> out.
__global__ __launch_bounds__(256) void pass2_kernel(
    const unsigned short* __restrict__ ebf,
    const float* __restrict__ sq,
    const float* __restrict__ sum_exp,
    const int* __restrict__ idxbuf,
    const int* __restrict__ offsets,
    const int* __restrict__ counts,
    double* __restrict__ partial2,
    unsigned* __restrict__ cnt2,
    unsigned* __restrict__ ticket,
    float* __restrict__ out)
{
    __shared__ __align__(16) char a_tile[128 * 128];
    __shared__ __align__(16) char b_tile[128 * 128];
    __shared__ double bsum[4];
    __shared__ unsigned bcnt[4];
    __shared__ bool isLast;

    const int L = blockIdx.x;
    const int NL = gridDim.x;
    const int tid = threadIdx.x;
    const int lane = tid & 63, wid = tid >> 6;
    const int cnt = counts[L], offs = offsets[L];
    const int wm = (wid >> 1) * 64, wn = (wid & 1) * 64;
    const int lhi = lane >> 4, llo = lane & 15;
    const char* ebfB = (const char*)ebf;
    const float E1 = 2.71828182845904523f;
    const float LN2 = 0.69314718055994531f;

    float lsum = 0.f; unsigned lcnt = 0;

    if (cnt > 1) {
        const int nSub = (cnt + 127) >> 7;
        for (int si = 0; si < nSub; ++si)
        for (int sj = si; sj < nSub; ++sj) {
            const int baseA = offs + si * 128, baseB = offs + sj * 128;
            const int cntA = min(128, cnt - si * 128);
            const int cntB = min(128, cnt - sj * 128);
            const float wgt = (si == sj) ? 1.f : 2.f;
            const unsigned wgtu = (si == sj) ? 1u : 2u;

            f32x4 acc[4][4];
            #pragma unroll
            for (int m = 0; m < 4; ++m)
                #pragma unroll
                for (int n = 0; n < 4; ++n)
                    acc[m][n] = (f32x4){0.f, 0.f, 0.f, 0.f};

            for (int c = 0; c < 2; ++c) {
                #pragma unroll
                for (int i2 = 0; i2 < 8; ++i2) {
                    int sl = tid + i2 * 256;
                    int tsel = sl >> 10;
                    int s = sl & 1023;
                    int r = s >> 3, j = s & 7;
                    int base = tsel ? baseB : baseA;
                    int cc = tsel ? cntB : cntA;
                    int gr = idxbuf[base + min(r, cc - 1)];
                    uint4 v = *(const uint4*)(ebfB + ((size_t)gr << 8) + c * 128 + (j << 4));
                    char* tp = tsel ? b_tile : a_tile;
                    *(uint4*)(tp + r * 128 + (((j << 4)) ^ ((r & 7) << 4))) = v;
                }
                __syncthreads();
                #pragma unroll
                for (int h = 0; h < 2; ++h) {
                    const int cb = h * 64 + lhi * 16;
                    bf16x8 af[4], bfr[4];
                    #pragma unroll
                    for (int m = 0; m < 4; ++m) {
                        int r = wm + m * 16 + llo;
                        af[m] = *(const bf16x8*)(a_tile + r * 128 + (cb ^ ((r & 7) << 4)));
                    }
                    #pragma unroll
                    for (int n = 0; n < 4; ++n) {
                        int r = wn + n * 16 + llo;
                        bfr[n] = *(const bf16x8*)(b_tile + r * 128 + (cb ^ ((r & 7) << 4)));
                    }
                    #pragma unroll
                    for (int m = 0; m < 4; ++m)
                        #pragma unroll
                        for (int n = 0; n < 4; ++n)
                            acc[m][n] = __builtin_amdgcn_mfma_f32_16x16x32_bf16(af[m], bfr[n], acc[m][n], 0, 0, 0);
                }
                __syncthreads();
            }

            int giA[4][4]; float sqA[4][4], seA[4][4]; bool vA[4][4];
            #pragma unroll
            for (int m = 0; m < 4; ++m)
                #pragma unroll
                for (int r = 0; r < 4; ++r) {
                    int lr = wm + m * 16 + lhi * 4 + r;
                    vA[m][r] = lr < cntA;
                    int gi = idxbuf[baseA + min(lr, cntA - 1)];
                    giA[m][r] = gi;
                    sqA[m][r] = sq[gi];
                    seA[m][r] = sum_exp[gi] * E1;
                }
            int gjB[4]; float sqB[4], seB[4]; bool vB[4];
            #pragma unroll
            for (int n = 0; n < 4; ++n) {
                int lc = wn + n * 16 + llo;
                vB[n] = lc < cntB;
                int gj = idxbuf[baseB + min(lc, cntB - 1)];
                gjB[n] = gj;
                sqB[n] = sq[gj];
                seB[n] = sum_exp[gj] * E1;
            }
            #pragma unroll
            for (int m = 0; m < 4; ++m)
                #pragma unroll
                for (int n = 0; n < 4; ++n)
                    #pragma unroll
                    for (int r = 0; r < 4; ++r) {
                        float g = acc[m][n][r];
                        float d2 = fmaxf(fmaf(-2.f, g, sqA[m][r] + sqB[n]), 0.f);
                        float dist = __builtin_amdgcn_sqrtf(d2) * LN2;
                        bool pos = vA[m][r] && vB[n] && (giA[m][r] != gjB[n]);
                        float Lv = __logf(seA[m][r] + seB[n]) + dist;
                        Lv = fmaxf(Lv, 0.f);
                        lsum += pos ? wgt * Lv * Lv : 0.f;
                        lcnt += pos ? wgtu : 0u;
                    }
        }
    }

    #pragma unroll
    for (int off = 1; off < 64; off <<= 1) {
        lsum += __shfl_xor(lsum, off, 64);
        lcnt += __shfl_xor(lcnt, off, 64);
    }
    if (lane == 0) { bsum[wid] = (double)lsum; bcnt[wid] = lcnt; }
    __syncthreads();
    if (tid == 0) {
        partial2[L] = bsum[0] + bsum[1] + bsum[2] + bsum[3];
        cnt2[L] = bcnt[0] + bcnt[1] + bcnt[2] + bcnt[3];
        __threadfence();
        isLast = (atomicAdd(ticket, 1u) == (unsigned)(NL - 1));
    }
    __syncthreads();

    if (isLast) {
        __threadfence();
        double tt = (tid < NL) ? partial2[tid] : 0.0;
        unsigned c = (tid < NL) ? cnt2[tid] : 0u;
        #pragma unroll
        for (int off = 1; off < 64; off <<= 1) {
            tt += __shfl_xor(tt, off, 64);
            c  += __shfl_xor(c, off, 64);
        }
        if (lane == 0) { bsum[wid] = tt; bcnt[wid] = c; }
        __syncthreads();
        if (tid == 0) {
            double s = bsum[0] + bsum[1] + bsum[2] + bsum[3];
            unsigned cc = bcnt[0] + bcnt[1] + bcnt[2] + bcnt[3];
            if (cc == 0) cc = 1;
            out[0] = (float)(s / (double)cc * 0.5);
        }
    }
}

extern "C" void kernel_launch(void* const* d_in, const int* in_sizes, int n_in,
                              void* d_out, int out_size, void* d_ws, size_t ws_size,
                              hipStream_t stream) {
    const float* e = (const float*)d_in[0];
    const int* labels = (const int*)d_in[1];
    const int N = in_sizes[1];                 // 8192
    const int nCb = N / 128;                   // 64
    const int nT = nCb * (nCb + 1) / 2;        // 2080
    const int NL = 256;
    const int nPrep = N / 32;                  // 256

    char* ws = (char*)d_ws;
    float*    sq       = (float*)ws;
    float*    sum_exp  = (float*)(ws + 4 * (size_t)N);
    unsigned short* ebf = (unsigned short*)(ws + 8 * (size_t)N);
    char*     p        = ws + 8 * (size_t)N + 256 * (size_t)N;
    int*      counts   = (int*)p;      p += NL * 4;
    int*      offsets  = (int*)p;      p += NL * 4;
    unsigned* ticket   = (unsigned*)p; p += 64;           // own cache line
    p = (char*)(((size_t)p + 7) & ~(size_t)7);
    double*   partial2 = (double*)p;   p += NL * 8;
    unsigned* cnt2     = (unsigned*)p; p += NL * 4;
    int*      idxbuf   = (int*)p;

    setup_kernel<<<nPrep + 1, 256, 0, stream>>>(e, labels, sq, (unsigned*)ebf,
                                                sum_exp, counts, offsets,
                                                idxbuf, ticket, N);
    pass1_kernel<<<nT, 512, 0, stream>>>(ebf, sq, labels, sum_exp, N, nCb, nT);
    pass2_kernel<<<NL, 256, 0, stream>>>(ebf, sq, sum_exp, idxbuf, offsets, counts,
                                         partial2, cnt2, ticket, (float*)d_out);
}